// Round 16
// baseline (88.757 us; speedup 1.0000x reference)
//
#include <hip/hip_runtime.h>
#include <math.h>

#define NN   1000
#define DD   128
#define CTXN 130
#define NEG_BIG (-1.0e30f)

// ============================================================================
// 6-dispatch pipeline, every emb-streaming kernel at high occupancy:
//  k1p (B*8x256): per-slice column sums (emb pass 1, proven ~6 TB/s) + probe
//  k1q (B x1024): mean merge -> query -> qproj + compaction + logits prefill
//  kB  (B*8x512): slim streaming compat->exp->outer-product (R15, unchanged)
//  k4a (B x512) : sum-merge -> wemb -> heads -> glimpse -> g2
//  k4b (B*8x512): balanced-compacted logits + raw expsum (max-free: |lg|<=10)
//  k5  (B x256) : lse = log(sum) ; out = logits - lse
// ws: meanp[B][1024] | qpt[B][1024] | wembp[B][8192] | stats[B][64]
//     | idx[B][1024] | cnt[B] | logits[B][1024] | lstats[B][8] | mflag
// Shared softmax shift C=0 in kB (|compat| << 80; fminf guard) -> plain-sum.
// ============================================================================

// ---------------- K1p: per-(b,s) partial column sums + mask probe ----------------
__global__ __launch_bounds__(256, 8)
void k1p_meanpart(const float* __restrict__ emb, const void* __restrict__ maskp,
                  float* __restrict__ meanp, int* __restrict__ mflag) {
    const int b = blockIdx.x >> 3, s = blockIdx.x & 7;
    const int t = threadIdx.x;
    const float* eb = emb + (size_t)b * (NN * DD);
    __shared__ __align__(16) float s_red[8 * 128];
    if (blockIdx.x == 0 && t == 0) {   // mask layout probe (int32: bytes 1 mod 4 all 0)
        const unsigned char* mb8 = (const unsigned char*)maskp;
        int any = 0;
        for (int k = 0; k < 64; ++k) any |= mb8[4 * k + 1];
        *mflag = (any == 0) ? 1 : 0;
    }
    const int c4 = t & 31, rg = t >> 5;
    float4 a = make_float4(0.f, 0.f, 0.f, 0.f);
    for (int nl = rg; nl < 125; nl += 8) {
        const float4 v = *(const float4*)(eb + (size_t)(s * 125 + nl) * DD + c4 * 4);
        a.x += v.x; a.y += v.y; a.z += v.z; a.w += v.w;
    }
    ((float4*)s_red)[rg * 32 + c4] = a;
    __syncthreads();
    if (t < 128) {
        float v = 0.f;
        #pragma unroll
        for (int g = 0; g < 8; ++g) v += s_red[g * 128 + t];
        meanp[(size_t)b * 1024 + s * 128 + t] = v;
    }
}

// ---------------- K1q: mean merge -> query -> qproj + compaction + prefill ----------------
__global__ __launch_bounds__(1024, 4)
void k1q_qproj(const float* __restrict__ meanp, const float* __restrict__ stepc,
               const void* __restrict__ maskp, const int* __restrict__ mflag,
               const float* __restrict__ Wn, const float* __restrict__ Wf,
               const float* __restrict__ Ws,
               float* __restrict__ qpt, int* __restrict__ idxv, int* __restrict__ cntv,
               float* __restrict__ logits) {
    const int b = blockIdx.x, t = threadIdx.x;
    const int w = t >> 6, lane = t & 63;
    __shared__ __align__(16) float S[1024];
    __shared__ float s_mean[128], s_q[128];
    __shared__ unsigned long long s_bal[16];
    __shared__ int s_woff[16];
    if (t < NN) logits[(size_t)b * 1024 + t] = NEG_BIG;   // prefill masked rows
    if (t < 128) {
        float v = 0.f;
        #pragma unroll
        for (int g = 0; g < 8; ++g) v += meanp[(size_t)b * 1024 + g * 128 + t];
        s_mean[t] = v * (1.0f / (float)NN);
    }
    __syncthreads();
    {   // query[d] = mean.Wf[:,d] + sc.Ws[:,d], 8-way split
        const int d = t & 127, p = t >> 7;
        float a = 0.f;
        for (int i = 16 * p; i < 16 * p + 16; ++i)
            a = fmaf(s_mean[i], Wf[i * DD + d], a);
        const float* scb = stepc + (size_t)b * CTXN;
        const int c0 = 16 * p, c1 = (p == 7) ? CTXN : 16 * p + 16;
        for (int c = c0; c < c1; ++c)
            a = fmaf(scb[c], Ws[c * DD + d], a);
        S[p * 128 + d] = a;
    }
    __syncthreads();
    if (t < 128) {
        float v = 0.f;
        #pragma unroll
        for (int p = 0; p < 8; ++p) v += S[p * 128 + t];
        s_q[t] = v;
    }
    __syncthreads();
    {   // qproj one-shot: thread (i = t&127, h = t>>7)
        const int i = t & 127, h = t >> 7;
        float a = 0.f;
        #pragma unroll
        for (int j = 0; j < 16; ++j)
            a = fmaf(Wn[i * 384 + h * 16 + j], s_q[h * 16 + j], a);
        qpt[(size_t)b * 1024 + h * 128 + i] = a * 0.25f;  // 1/sqrt(16)
    }
    // ---- compaction: unmasked row indices, ascending ----
    {
        const int misint = *mflag;
        const unsigned char* mk8 = (const unsigned char*)maskp + (size_t)b * NN;
        const int* mk32 = (const int*)maskp + (size_t)b * NN;
        int um = 0;
        if (t < NN) um = misint ? (mk32[t] == 0) : (mk8[t] == 0);
        const unsigned long long bal = __ballot(um);
        if (lane == 0) s_bal[w] = bal;
        __syncthreads();
        if (t == 0) {
            int o = 0;
            #pragma unroll
            for (int w2 = 0; w2 < 16; ++w2) {
                s_woff[w2] = o;
                o += (int)__popcll(s_bal[w2]);
            }
            cntv[b] = o;
        }
        __syncthreads();
        if (um) {
            const int pos = s_woff[w] +
                (int)__popcll(bal & ((lane == 0) ? 0ULL : (~0ULL >> (64 - lane))));
            idxv[(size_t)b * 1024 + pos] = t;
        }
    }
}

// ---------------- KB: slim streaming over balanced compacted slices (R15) ----------------
__global__ __launch_bounds__(512, 4)
void kB_stream(const float* __restrict__ emb, const float* __restrict__ qpt,
               const int* __restrict__ idxv, const int* __restrict__ cntv,
               float* __restrict__ wembp, float* __restrict__ stats) {
    const int b = blockIdx.x >> 3, s = blockIdx.x & 7;
    const int t = threadIdx.x, w = t >> 6, lane = t & 63;
    const int rg = lane >> 4, cl = lane & 15;
    const int cnt = cntv[b];
    const int lo = (s * cnt) >> 3;
    const int hi = ((s + 1) * cnt) >> 3;
    const int nrows = hi - lo;
    const float* eb = emb + (size_t)b * (NN * DD);
    __shared__ __align__(16) float s_qpT[1024];
    __shared__ __align__(16) float s_part[8 * 8 * 132];
    __shared__ float s_sumw[64];
    __shared__ int s_idx[128];
    for (int i = t; i < 1024; i += 512) s_qpT[i] = qpt[(size_t)b * 1024 + i];
    if (t < 128) s_idx[t] = (t < nrows) ? idxv[(size_t)b * 1024 + lo + t] : 0;
    __syncthreads();
    const int h0 = 2 * rg, h1 = 2 * rg + 1;
    const float4 qa0 = *(const float4*)&s_qpT[h0 * 128 + cl * 8];
    const float4 qa1 = *(const float4*)&s_qpT[h0 * 128 + cl * 8 + 4];
    const float4 qb0 = *(const float4*)&s_qpT[h1 * 128 + cl * 8];
    const float4 qb1 = *(const float4*)&s_qpT[h1 * 128 + cl * 8 + 4];
    float4 a0A = make_float4(0.f,0.f,0.f,0.f), a0B = a0A;
    float4 a1A = a0A, a1B = a0A;
    float ps0 = 0.f, ps1 = 0.f;
    const int niter = (nrows + 7) >> 3;
    for (int it = 0; it < niter; ++it) {
        const int rp = it * 8 + w;
        const bool valid = (rp < nrows);
        const int n = s_idx[rp & 127];
        float4 e0 = make_float4(0.f,0.f,0.f,0.f), e1 = e0;
        if (valid) {
            e0 = *(const float4*)(eb + (size_t)n * DD + cl * 8);
            e1 = *(const float4*)(eb + (size_t)n * DD + cl * 8 + 4);
        }
        float c0 = e0.x * qa0.x;
        c0 = fmaf(e0.y, qa0.y, c0); c0 = fmaf(e0.z, qa0.z, c0); c0 = fmaf(e0.w, qa0.w, c0);
        c0 = fmaf(e1.x, qa1.x, c0); c0 = fmaf(e1.y, qa1.y, c0);
        c0 = fmaf(e1.z, qa1.z, c0); c0 = fmaf(e1.w, qa1.w, c0);
        float c1 = e0.x * qb0.x;
        c1 = fmaf(e0.y, qb0.y, c1); c1 = fmaf(e0.z, qb0.z, c1); c1 = fmaf(e0.w, qb0.w, c1);
        c1 = fmaf(e1.x, qb1.x, c1); c1 = fmaf(e1.y, qb1.y, c1);
        c1 = fmaf(e1.z, qb1.z, c1); c1 = fmaf(e1.w, qb1.w, c1);
        c0 += __shfl_xor(c0, 1, 16); c1 += __shfl_xor(c1, 1, 16);
        c0 += __shfl_xor(c0, 2, 16); c1 += __shfl_xor(c1, 2, 16);
        c0 += __shfl_xor(c0, 4, 16); c1 += __shfl_xor(c1, 4, 16);
        c0 += __shfl_xor(c0, 8, 16); c1 += __shfl_xor(c1, 8, 16);
        const float p0 = valid ? expf(fminf(c0, 80.f)) : 0.f;
        const float p1 = valid ? expf(fminf(c1, 80.f)) : 0.f;
        ps0 += p0; ps1 += p1;
        a0A.x = fmaf(p0, e0.x, a0A.x); a0A.y = fmaf(p0, e0.y, a0A.y);
        a0A.z = fmaf(p0, e0.z, a0A.z); a0A.w = fmaf(p0, e0.w, a0A.w);
        a0B.x = fmaf(p0, e1.x, a0B.x); a0B.y = fmaf(p0, e1.y, a0B.y);
        a0B.z = fmaf(p0, e1.z, a0B.z); a0B.w = fmaf(p0, e1.w, a0B.w);
        a1A.x = fmaf(p1, e0.x, a1A.x); a1A.y = fmaf(p1, e0.y, a1A.y);
        a1A.z = fmaf(p1, e0.z, a1A.z); a1A.w = fmaf(p1, e0.w, a1A.w);
        a1B.x = fmaf(p1, e1.x, a1B.x); a1B.y = fmaf(p1, e1.y, a1B.y);
        a1B.z = fmaf(p1, e1.z, a1B.z); a1B.w = fmaf(p1, e1.w, a1B.w);
    }
    *(float4*)&s_part[(w * 8 + h0) * 132 + cl * 8]     = a0A;
    *(float4*)&s_part[(w * 8 + h0) * 132 + cl * 8 + 4] = a0B;
    *(float4*)&s_part[(w * 8 + h1) * 132 + cl * 8]     = a1A;
    *(float4*)&s_part[(w * 8 + h1) * 132 + cl * 8 + 4] = a1B;
    if (cl == 0) { s_sumw[w * 8 + h0] = ps0; s_sumw[w * 8 + h1] = ps1; }
    __syncthreads();
    for (int i = t; i < 1024; i += 512) {
        const int h = i >> 7, c = i & 127;
        float v = 0.f;
        #pragma unroll
        for (int w2 = 0; w2 < 8; ++w2) v += s_part[(w2 * 8 + h) * 132 + c];
        wembp[(size_t)b * 8192 + s * 1024 + i] = v;
    }
    if (t < 8) {
        float v = 0.f;
        #pragma unroll
        for (int w2 = 0; w2 < 8; ++w2) v += s_sumw[w2 * 8 + t];
        stats[(size_t)b * 64 + s * 8 + t] = v;
    }
}

// ---------------- K4a: sum-merge -> wemb -> heads -> glimpse -> g2 ----------------
__global__ __launch_bounds__(512, 4)
void k4a_g2(const float* __restrict__ wembp, const float* __restrict__ stats,
            const float* __restrict__ Wn, const float* __restrict__ Wo,
            float* __restrict__ g2v) {
    const int b = blockIdx.x, t = threadIdx.x;
    __shared__ float s_dinv[8];
    __shared__ float s_wemb[8 * 130];
    __shared__ float s_red[512];
    __shared__ float s_h[128], s_gl[128];
    if (t < 8) {
        float den = 0.f;
        #pragma unroll
        for (int ss = 0; ss < 8; ++ss) den += stats[(size_t)b * 64 + ss * 8 + t];
        s_dinv[t] = 1.0f / den;
    }
    __syncthreads();
    for (int idx = t; idx < 1024; idx += 512) {
        const int h = idx >> 7, i = idx & 127;
        float v = 0.f;
        #pragma unroll
        for (int ss = 0; ss < 8; ++ss)
            v += wembp[(size_t)b * 8192 + ss * 1024 + idx];
        s_wemb[h * 130 + i] = v * s_dinv[h];
    }
    __syncthreads();
    {   // heads[j] = sum_i Wv[i,j] wemb[j>>4][i], 4-way i-split
        const int j = t & 127, p = t >> 7;
        float a = 0.f;
        for (int i = 32 * p; i < 32 * p + 32; ++i)
            a = fmaf(Wn[i * 384 + 128 + j], s_wemb[(j >> 4) * 130 + i], a);
        s_red[p * 128 + j] = a;
    }
    __syncthreads();
    if (t < 128) s_h[t] = s_red[t] + s_red[128 + t] + s_red[256 + t] + s_red[384 + t];
    __syncthreads();
    {   // glimpse[d] = sum_j heads[j] Wo[j,d]
        const int d = t & 127, p = t >> 7;
        float a = 0.f;
        for (int j = 32 * p; j < 32 * p + 32; ++j)
            a = fmaf(s_h[j], Wo[j * DD + d], a);
        s_red[p * 128 + d] = a;
    }
    __syncthreads();
    if (t < 128) s_gl[t] = s_red[t] + s_red[128 + t] + s_red[256 + t] + s_red[384 + t];
    __syncthreads();
    {   // g2[i] = (1/sqrt(128)) sum_d Wl[i,d] glimpse[d]
        const int i = t & 127, p = t >> 7;
        float a = 0.f;
        for (int d = 32 * p; d < 32 * p + 32; ++d)
            a = fmaf(Wn[i * 384 + 256 + d], s_gl[d], a);
        s_red[p * 128 + i] = a;
    }
    __syncthreads();
    if (t < 128)
        g2v[(size_t)b * 128 + t] =
            (s_red[t] + s_red[128 + t] + s_red[256 + t] + s_red[384 + t]) * 0.08838834764831845f;
}

// ---------------- K4b: balanced-compacted logits + raw expsum ----------------
// Max-free LSE partials are exact: logits = 10*tanh(.) in [-10,10], exp in
// [4.5e-5, 2.2e4], sums <= 2.2e7 -- no overflow/underflow concern in fp32.
__global__ __launch_bounds__(512, 4)
void k4b_logits(const float* __restrict__ emb, const float* __restrict__ g2v,
                const int* __restrict__ idxv, const int* __restrict__ cntv,
                float* __restrict__ logits, float* __restrict__ lstats) {
    const int b = blockIdx.x >> 3, s = blockIdx.x & 7;
    const int t = threadIdx.x, w = t >> 6, lane = t & 63;
    const int rg = lane >> 4, cl = lane & 15;
    const int cnt = cntv[b];
    const int lo = (s * cnt) >> 3;
    const int hi = ((s + 1) * cnt) >> 3;
    const int nrows = hi - lo;
    const float* eb = emb + (size_t)b * (NN * DD);
    __shared__ __align__(16) float s_g2[128];
    __shared__ int s_idx[128];
    __shared__ float s_ws[8];
    if (t < 128) {
        s_g2[t] = g2v[(size_t)b * 128 + t];
        s_idx[t] = (t < nrows) ? idxv[(size_t)b * 1024 + lo + t] : 0;
    }
    __syncthreads();
    const float4 ga = *(const float4*)&s_g2[cl * 8];
    const float4 gb = *(const float4*)&s_g2[cl * 8 + 4];
    float lsum = 0.f;
    const int niter = (nrows + 31) >> 5;   // 32 positions per iteration
    for (int it = 0; it < niter; ++it) {
        const int rp = it * 32 + w * 4 + rg;
        const bool valid = (rp < nrows);
        const int n = s_idx[rp & 127];
        float a = 0.f;
        if (valid) {
            const float4 e0 = *(const float4*)(eb + (size_t)n * DD + cl * 8);
            const float4 e1 = *(const float4*)(eb + (size_t)n * DD + cl * 8 + 4);
            a = e0.x * ga.x;
            a = fmaf(e0.y, ga.y, a);
            a = fmaf(e0.z, ga.z, a);
            a = fmaf(e0.w, ga.w, a);
            a = fmaf(e1.x, gb.x, a);
            a = fmaf(e1.y, gb.y, a);
            a = fmaf(e1.z, gb.z, a);
            a = fmaf(e1.w, gb.w, a);
        }
        a += __shfl_xor(a, 1, 16);
        a += __shfl_xor(a, 2, 16);
        a += __shfl_xor(a, 4, 16);
        a += __shfl_xor(a, 8, 16);
        if (cl == 0 && valid) {
            const float lg = 10.0f * tanhf(a);
            logits[(size_t)b * 1024 + n] = lg;
            lsum += expf(lg);
        }
    }
    #pragma unroll
    for (int o = 32; o; o >>= 1) lsum += __shfl_xor(lsum, o, 64);
    if (lane == 0) s_ws[w] = lsum;
    __syncthreads();
    if (t == 0) {
        float v = 0.f;
        #pragma unroll
        for (int w2 = 0; w2 < 8; ++w2) v += s_ws[w2];
        lstats[(size_t)b * 8 + s] = v;
    }
}

// ---------------- K5: lse merge -> out ----------------
__global__ __launch_bounds__(256, 8)
void k5_norm(const float* __restrict__ logits, const float* __restrict__ lstats,
             float* __restrict__ out) {
    const int b = blockIdx.x, t = threadIdx.x;
    float den = 0.f;
    #pragma unroll
    for (int s = 0; s < 8; ++s) den += lstats[(size_t)b * 8 + s];
    const float lse = logf(den);
    for (int n = t; n < NN; n += 256)
        out[(size_t)b * NN + n] = logits[(size_t)b * 1024 + n] - lse;
}

extern "C" void kernel_launch(void* const* d_in, const int* in_sizes, int n_in,
                              void* d_out, int out_size, void* d_ws, size_t ws_size,
                              hipStream_t stream) {
    const float* emb   = (const float*)d_in[0];
    const float* stepc = (const float*)d_in[1];
    const void*  mask  = (const void*)d_in[2];
    const float* Wn = (const float*)d_in[3];
    const float* Wf = (const float*)d_in[4];
    const float* Ws = (const float*)d_in[5];
    const float* Wo = (const float*)d_in[6];
    float* out = (float*)d_out;
    const int B = in_sizes[0] / (NN * DD);  // 256

    float* wsf = (float*)d_ws;
    const size_t n_meanp = (size_t)B * 1024;
    const size_t n_qpt   = (size_t)B * 1024;
    const size_t n_wembp = (size_t)B * 8192;
    const size_t n_stats = (size_t)B * 64;
    const size_t n_idx   = (size_t)B * 1024;
    const size_t n_g2    = (size_t)B * 128;
    const size_t n_logit = (size_t)B * 1024;
    const size_t n_lst   = (size_t)B * 8;

    float* meanp  = wsf;
    float* qpt    = meanp + n_meanp;
    float* wembp  = qpt + n_qpt;
    float* stats  = wembp + n_wembp;
    float* g2v    = stats + n_stats;
    float* logits = g2v + n_g2;
    float* lstats = logits + n_logit;
    int*   idxv   = (int*)(lstats + n_lst);
    int*   cntv   = idxv + n_idx;
    int*   mflag  = cntv + B;

    k1p_meanpart<<<B * 8, 256, 0, stream>>>(emb, mask, meanp, mflag);
    k1q_qproj   <<<B,     1024, 0, stream>>>(meanp, stepc, mask, mflag, Wn, Wf, Ws,
                                             qpt, idxv, cntv, logits);
    kB_stream   <<<B * 8, 512, 0, stream>>>(emb, qpt, idxv, cntv, wembp, stats);
    k4a_g2      <<<B,     512, 0, stream>>>(wembp, stats, Wn, Wo, g2v);
    k4b_logits  <<<B * 8, 512, 0, stream>>>(emb, g2v, idxv, cntv, logits, lstats);
    k5_norm     <<<B,     256, 0, stream>>>(logits, lstats, out);
}

// Round 17
// 81.371 us; speedup vs baseline: 1.0908x; 1.0908x over previous
//
#include <hip/hip_runtime.h>
#include <math.h>

#define NN   1000
#define DD   128
#define CTXN 130
#define NEG_BIG (-1.0e30f)

// ============================================================================
// 3-dispatch pipeline (R15 champion + k4 micro-cuts):
//  k1_fused (B x1024): emb -> mean -> query -> qproj[h][i] + row compaction
//  kB       (B*8x512): slim streaming over balanced compacted rows; lane owns
//                      2 heads x 8 cols (~60 VGPR, no spill at (512,4)) ->
//                      4 blk/CU, 32 waves/CU, XCD-balanced slices.
//  k4_fused (B x1024): sum-merge -> heads -> glimpse -> g2 -> logits (DYNAMIC
//                      trip count over compacted rows) -> MAX-FREE log_softmax
//                      (|logits|<=10 so exp in [4.5e-5,2.2e4]; exp(NEG_BIG)=0)
// ws: qpt[B][1024] | wembp[B][8][1024] | stats[B][64] | idx[B][1024] | cnt[B]
// Shared softmax shift C=0 (|compat| << 80; fminf guard) -> plain-sum merge.
// Lessons: dispatch boundary ~2-3us (R16); (512,4) caps VGPR=64 (R11);
// blockIdx%8 = XCD -> balance slices (R13).
// ============================================================================

// ---------------- K1': mean + query + qproj + mask compaction ----------------
__global__ __launch_bounds__(1024, 4)
void k1_fused(const float* __restrict__ emb, const float* __restrict__ stepc,
              const void* __restrict__ maskp,
              const float* __restrict__ Wn, const float* __restrict__ Wf,
              const float* __restrict__ Ws,
              float* __restrict__ qpt, int* __restrict__ idxv, int* __restrict__ cntv) {
    const int b = blockIdx.x, t = threadIdx.x;
    const int w = t >> 6, lane = t & 63;
    const float* eb = emb + (size_t)b * (NN * DD);
    __shared__ __align__(16) float S[4096];
    __shared__ float s_mean[128], s_q[128];
    __shared__ int s_misint;
    __shared__ unsigned long long s_bal[16];
    __shared__ int s_woff[16];
    if (t == 0) {   // mask layout probe (int32: bytes 1 mod 4 all 0)
        const unsigned char* mb8 = (const unsigned char*)maskp;
        int any = 0;
        for (int k = 0; k < 64; ++k) any |= mb8[4 * k + 1];
        s_misint = (any == 0) ? 1 : 0;
    }
    {   // mean: 32 row-groups x 32 float4-columns
        const int c4 = t & 31, g = t >> 5;
        float4 a = make_float4(0.f, 0.f, 0.f, 0.f);
        for (int r = g; r < NN; r += 32) {
            const float4 v = *(const float4*)(eb + (size_t)r * DD + c4 * 4);
            a.x += v.x; a.y += v.y; a.z += v.z; a.w += v.w;
        }
        ((float4*)S)[g * 32 + c4] = a;
    }
    __syncthreads();
    if (t < 128) {
        float v = 0.f;
        #pragma unroll
        for (int g = 0; g < 32; ++g) v += S[g * 128 + t];
        s_mean[t] = v * (1.0f / (float)NN);
    }
    __syncthreads();
    {   // query[d] = mean.Wf[:,d] + sc.Ws[:,d], 8-way split
        const int d = t & 127, p = t >> 7;
        float a = 0.f;
        for (int i = 16 * p; i < 16 * p + 16; ++i)
            a = fmaf(s_mean[i], Wf[i * DD + d], a);
        const float* scb = stepc + (size_t)b * CTXN;
        const int c0 = 16 * p, c1 = (p == 7) ? CTXN : 16 * p + 16;
        for (int c = c0; c < c1; ++c)
            a = fmaf(scb[c], Ws[c * DD + d], a);
        S[p * 128 + d] = a;
    }
    __syncthreads();
    if (t < 128) {
        float v = 0.f;
        #pragma unroll
        for (int p = 0; p < 8; ++p) v += S[p * 128 + t];
        s_q[t] = v;
    }
    __syncthreads();
    {   // qproj one-shot: thread (i = t&127, h = t>>7)
        const int i = t & 127, h = t >> 7;
        float a = 0.f;
        #pragma unroll
        for (int j = 0; j < 16; ++j)
            a = fmaf(Wn[i * 384 + h * 16 + j], s_q[h * 16 + j], a);
        qpt[(size_t)b * 1024 + h * 128 + i] = a * 0.25f;  // 1/sqrt(16)
    }
    // ---- compaction: unmasked row indices, ascending ----
    {
        const unsigned char* mk8 = (const unsigned char*)maskp + (size_t)b * NN;
        const int* mk32 = (const int*)maskp + (size_t)b * NN;
        int um = 0;
        if (t < NN) um = s_misint ? (mk32[t] == 0) : (mk8[t] == 0);
        const unsigned long long bal = __ballot(um);
        if (lane == 0) s_bal[w] = bal;
        __syncthreads();
        if (t == 0) {
            int o = 0;
            #pragma unroll
            for (int w2 = 0; w2 < 16; ++w2) {
                s_woff[w2] = o;
                o += (int)__popcll(s_bal[w2]);
            }
            cntv[b] = o;
        }
        __syncthreads();
        if (um) {
            const int pos = s_woff[w] +
                (int)__popcll(bal & ((lane == 0) ? 0ULL : (~0ULL >> (64 - lane))));
            idxv[(size_t)b * 1024 + pos] = t;
        }
    }
}

// ---------------- KB: slim streaming over balanced compacted slices ----------------
// lane = (rg, cl): rg in [0,4) = head PAIR (heads 2rg, 2rg+1); cl = col octet.
// All 4 rg groups process the SAME row (loads L1-shared); wave w does compact
// position it*8 + w. ~60 VGPR -> no spill at (512,4); 4 blk/CU, 100% occ.
__global__ __launch_bounds__(512, 4)
void kB_stream(const float* __restrict__ emb, const float* __restrict__ qpt,
               const int* __restrict__ idxv, const int* __restrict__ cntv,
               float* __restrict__ wembp, float* __restrict__ stats) {
    const int b = blockIdx.x >> 3, s = blockIdx.x & 7;
    const int t = threadIdx.x, w = t >> 6, lane = t & 63;
    const int rg = lane >> 4, cl = lane & 15;
    const int cnt = cntv[b];
    const int lo = (s * cnt) >> 3;          // balanced: slice s gets ~cnt/8 rows
    const int hi = ((s + 1) * cnt) >> 3;
    const int nrows = hi - lo;              // <= 125
    const float* eb = emb + (size_t)b * (NN * DD);
    __shared__ __align__(16) float s_qpT[1024];         // 4 KB
    __shared__ __align__(16) float s_part[8 * 8 * 132]; // 33.8 KB [w][h][132]
    __shared__ float s_sumw[64];
    __shared__ int s_idx[128];
    for (int i = t; i < 1024; i += 512) s_qpT[i] = qpt[(size_t)b * 1024 + i];
    if (t < 128) s_idx[t] = (t < nrows) ? idxv[(size_t)b * 1024 + lo + t] : 0;
    __syncthreads();
    const int h0 = 2 * rg, h1 = 2 * rg + 1;
    const float4 qa0 = *(const float4*)&s_qpT[h0 * 128 + cl * 8];
    const float4 qa1 = *(const float4*)&s_qpT[h0 * 128 + cl * 8 + 4];
    const float4 qb0 = *(const float4*)&s_qpT[h1 * 128 + cl * 8];
    const float4 qb1 = *(const float4*)&s_qpT[h1 * 128 + cl * 8 + 4];
    float4 a0A = make_float4(0.f,0.f,0.f,0.f), a0B = a0A;   // head h0, cols lo/hi
    float4 a1A = a0A, a1B = a0A;                            // head h1
    float ps0 = 0.f, ps1 = 0.f;
    const int niter = (nrows + 7) >> 3;     // uniform; ~8 typical
    for (int it = 0; it < niter; ++it) {
        const int rp = it * 8 + w;          // wave-w's compact position
        const bool valid = (rp < nrows);
        const int n = s_idx[rp & 127];
        float4 e0 = make_float4(0.f,0.f,0.f,0.f), e1 = e0;
        if (valid) {
            e0 = *(const float4*)(eb + (size_t)n * DD + cl * 8);
            e1 = *(const float4*)(eb + (size_t)n * DD + cl * 8 + 4);
        }
        float c0 = e0.x * qa0.x;
        c0 = fmaf(e0.y, qa0.y, c0); c0 = fmaf(e0.z, qa0.z, c0); c0 = fmaf(e0.w, qa0.w, c0);
        c0 = fmaf(e1.x, qa1.x, c0); c0 = fmaf(e1.y, qa1.y, c0);
        c0 = fmaf(e1.z, qa1.z, c0); c0 = fmaf(e1.w, qa1.w, c0);
        float c1 = e0.x * qb0.x;
        c1 = fmaf(e0.y, qb0.y, c1); c1 = fmaf(e0.z, qb0.z, c1); c1 = fmaf(e0.w, qb0.w, c1);
        c1 = fmaf(e1.x, qb1.x, c1); c1 = fmaf(e1.y, qb1.y, c1);
        c1 = fmaf(e1.z, qb1.z, c1); c1 = fmaf(e1.w, qb1.w, c1);
        c0 += __shfl_xor(c0, 1, 16); c1 += __shfl_xor(c1, 1, 16);
        c0 += __shfl_xor(c0, 2, 16); c1 += __shfl_xor(c1, 2, 16);
        c0 += __shfl_xor(c0, 4, 16); c1 += __shfl_xor(c1, 4, 16);
        c0 += __shfl_xor(c0, 8, 16); c1 += __shfl_xor(c1, 8, 16);
        const float p0 = valid ? expf(fminf(c0, 80.f)) : 0.f;
        const float p1 = valid ? expf(fminf(c1, 80.f)) : 0.f;
        ps0 += p0; ps1 += p1;
        a0A.x = fmaf(p0, e0.x, a0A.x); a0A.y = fmaf(p0, e0.y, a0A.y);
        a0A.z = fmaf(p0, e0.z, a0A.z); a0A.w = fmaf(p0, e0.w, a0A.w);
        a0B.x = fmaf(p0, e1.x, a0B.x); a0B.y = fmaf(p0, e1.y, a0B.y);
        a0B.z = fmaf(p0, e1.z, a0B.z); a0B.w = fmaf(p0, e1.w, a0B.w);
        a1A.x = fmaf(p1, e0.x, a1A.x); a1A.y = fmaf(p1, e0.y, a1A.y);
        a1A.z = fmaf(p1, e0.z, a1A.z); a1A.w = fmaf(p1, e0.w, a1A.w);
        a1B.x = fmaf(p1, e1.x, a1B.x); a1B.y = fmaf(p1, e1.y, a1B.y);
        a1B.z = fmaf(p1, e1.z, a1B.z); a1B.w = fmaf(p1, e1.w, a1B.w);
    }
    // direct per-lane write (no shfl epilogue): lane covers (h0,h1) x cols cl*8..+8
    *(float4*)&s_part[(w * 8 + h0) * 132 + cl * 8]     = a0A;
    *(float4*)&s_part[(w * 8 + h0) * 132 + cl * 8 + 4] = a0B;
    *(float4*)&s_part[(w * 8 + h1) * 132 + cl * 8]     = a1A;
    *(float4*)&s_part[(w * 8 + h1) * 132 + cl * 8 + 4] = a1B;
    if (cl == 0) { s_sumw[w * 8 + h0] = ps0; s_sumw[w * 8 + h1] = ps1; }
    __syncthreads();
    for (int i = t; i < 1024; i += 512) {
        const int h = i >> 7, c = i & 127;
        float v = 0.f;
        #pragma unroll
        for (int w2 = 0; w2 < 8; ++w2) v += s_part[(w2 * 8 + h) * 132 + c];
        wembp[(size_t)b * 8192 + s * 1024 + i] = v;   // [b][s][h][i]
    }
    if (t < 8) {
        float v = 0.f;
        #pragma unroll
        for (int w2 = 0; w2 < 8; ++w2) v += s_sumw[w2 * 8 + t];
        stats[(size_t)b * 64 + s * 8 + t] = v;
    }
}

// ---------------- K4': sum-merge -> g2 -> logits -> max-free log_softmax ----------------
__global__ __launch_bounds__(1024, 4)
void k4_fused(const float* __restrict__ emb, const float* __restrict__ wembp,
              const float* __restrict__ stats,
              const float* __restrict__ Wn, const float* __restrict__ Wo,
              const int* __restrict__ idxv, const int* __restrict__ cntv,
              float* __restrict__ out) {
    const int b = blockIdx.x, t = threadIdx.x;
    const int w = t >> 6, lane = t & 63;
    const int rg = lane >> 4, cl = lane & 15;
    const float* eb = emb + (size_t)b * (NN * DD);
    __shared__ float s_dinv[8];
    __shared__ float s_wemb[8 * 130];
    __shared__ __align__(16) float s_red[1024];
    __shared__ float s_h[128], s_gl[128], s_g2[128];
    __shared__ float s_logits[1000];
    __shared__ int s_idxf[1024];
    __shared__ float s_r2[32];
    __shared__ float s_lse;
    const int cnt = cntv[b];
    if (t < NN) s_logits[t] = NEG_BIG;           // masked rows stay NEG_BIG
    s_idxf[t] = (t < cnt) ? idxv[(size_t)b * 1024 + t] : 0;
    // ---- merge: shared shift C=0 -> den[h] = sum_s psum_s[h] ----
    if (t < 8) {
        float den = 0.f;
        #pragma unroll
        for (int ss = 0; ss < 8; ++ss) den += stats[(size_t)b * 64 + ss * 8 + t];
        s_dinv[t] = 1.0f / den;
    }
    __syncthreads();
    {   // wemb[h][i] = (sum_s wembp_s) * dinv[h]
        const int h = t >> 7, i = t & 127;
        float v = 0.f;
        #pragma unroll
        for (int ss = 0; ss < 8; ++ss)
            v += wembp[(size_t)b * 8192 + ss * 1024 + t];
        s_wemb[h * 130 + i] = v * s_dinv[h];
    }
    __syncthreads();
    {   // heads[j] = sum_i Wv[i,j] wemb[j>>4][i], 8-way i-split
        const int j = t & 127, p = t >> 7;
        float a = 0.f;
        for (int i = 16 * p; i < 16 * p + 16; ++i)
            a = fmaf(Wn[i * 384 + 128 + j], s_wemb[(j >> 4) * 130 + i], a);
        s_red[p * 128 + j] = a;
    }
    __syncthreads();
    if (t < 128) {
        float v = 0.f;
        #pragma unroll
        for (int p = 0; p < 8; ++p) v += s_red[p * 128 + t];
        s_h[t] = v;
    }
    __syncthreads();
    {   // glimpse[d] = sum_j heads[j] Wo[j,d]
        const int d = t & 127, p = t >> 7;
        float a = 0.f;
        for (int j = 16 * p; j < 16 * p + 16; ++j)
            a = fmaf(s_h[j], Wo[j * DD + d], a);
        s_red[p * 128 + d] = a;
    }
    __syncthreads();
    if (t < 128) {
        float v = 0.f;
        #pragma unroll
        for (int p = 0; p < 8; ++p) v += s_red[p * 128 + t];
        s_gl[t] = v;
    }
    __syncthreads();
    {   // g2[i] = (1/sqrt(128)) sum_d Wl[i,d] glimpse[d]
        const int i = t & 127, p = t >> 7;
        float a = 0.f;
        for (int d = 16 * p; d < 16 * p + 16; ++d)
            a = fmaf(Wn[i * 384 + 256 + d], s_gl[d], a);
        s_red[p * 128 + i] = a;
    }
    __syncthreads();
    if (t < 128) {
        float v = 0.f;
        #pragma unroll
        for (int p = 0; p < 8; ++p) v += s_red[p * 128 + t];
        s_g2[t] = v * 0.08838834764831845f;
    }
    __syncthreads();
    // ---- logits over compacted rows: DYNAMIC trip count (cnt ~ 500, not 1024) ----
    {
        const float4 ga = *(const float4*)&s_g2[cl * 8];
        const float4 gb = *(const float4*)&s_g2[cl * 8 + 4];
        const int niterL = (cnt + 63) >> 6;     // 64 positions per iteration
        for (int it = 0; it < niterL; ++it) {
            const int pos = it * 64 + w * 4 + rg;
            const bool valid = (pos < cnt);
            const int n = s_idxf[pos & 1023];
            float a = 0.f;
            if (valid) {
                const float4 e0 = *(const float4*)(eb + (size_t)n * DD + cl * 8);
                const float4 e1 = *(const float4*)(eb + (size_t)n * DD + cl * 8 + 4);
                a = e0.x * ga.x;
                a = fmaf(e0.y, ga.y, a);
                a = fmaf(e0.z, ga.z, a);
                a = fmaf(e0.w, ga.w, a);
                a = fmaf(e1.x, gb.x, a);
                a = fmaf(e1.y, gb.y, a);
                a = fmaf(e1.z, gb.z, a);
                a = fmaf(e1.w, gb.w, a);
            }
            a += __shfl_xor(a, 1, 16);
            a += __shfl_xor(a, 2, 16);
            a += __shfl_xor(a, 4, 16);
            a += __shfl_xor(a, 8, 16);
            if (cl == 0 && valid)
                s_logits[n] = 10.0f * tanhf(a);
        }
    }
    __syncthreads();
    // ---- max-free log_softmax: |logits| <= 10 -> exp in [4.5e-5, 2.2e4];
    //      masked rows: expf(NEG_BIG) = 0 exactly. (Validated in R16's k4b.)
    {
        float sum = (t < NN) ? expf(s_logits[t]) : 0.f;
        #pragma unroll
        for (int o = 32; o; o >>= 1) sum += __shfl_xor(sum, o, 64);
        if (lane == 0) s_r2[w] = sum;
        __syncthreads();
        if (t == 0) {
            float ss = 0.f;
            #pragma unroll
            for (int i = 0; i < 16; ++i) ss += s_r2[i];
            s_lse = logf(ss);
        }
        __syncthreads();
        if (t < NN) out[(size_t)b * NN + t] = s_logits[t] - s_lse;
    }
}

extern "C" void kernel_launch(void* const* d_in, const int* in_sizes, int n_in,
                              void* d_out, int out_size, void* d_ws, size_t ws_size,
                              hipStream_t stream) {
    const float* emb   = (const float*)d_in[0];
    const float* stepc = (const float*)d_in[1];
    const void*  mask  = (const void*)d_in[2];
    const float* Wn = (const float*)d_in[3];
    const float* Wf = (const float*)d_in[4];
    const float* Ws = (const float*)d_in[5];
    const float* Wo = (const float*)d_in[6];
    float* out = (float*)d_out;
    const int B = in_sizes[0] / (NN * DD);  // 256

    float* wsf = (float*)d_ws;
    const size_t n_qpt   = (size_t)B * 1024;
    const size_t n_wembp = (size_t)B * 8192;
    const size_t n_stats = (size_t)B * 64;
    const size_t n_idx   = (size_t)B * 1024;

    float* qpt   = wsf;
    float* wembp = qpt + n_qpt;
    float* stats = wembp + n_wembp;
    int*   idxv  = (int*)(stats + n_stats);
    int*   cntv  = idxv + n_idx;

    k1_fused <<<B,     1024, 0, stream>>>(emb, stepc, mask, Wn, Wf, Ws, qpt, idxv, cntv);
    kB_stream<<<B * 8, 512,  0, stream>>>(emb, qpt, idxv, cntv, wembp, stats);
    k4_fused <<<B,     1024, 0, stream>>>(emb, wembp, stats, Wn, Wo, idxv, cntv, out);
}

// Round 18
// 80.400 us; speedup vs baseline: 1.1039x; 1.0121x over previous
//
#include <hip/hip_runtime.h>
#include <math.h>

#define NN   1000
#define DD   128
#define CTXN 130
#define NEG_BIG (-1.0e30f)

// ============================================================================
// 3-dispatch pipeline (R17 champion + headsp linearity fold):
//  k1_fused (B x1024): emb -> mean -> query -> qproj[h][i] + row compaction
//  kB       (B*8x512): slim streaming over balanced compacted rows (2 heads x
//                      8 cols per lane, <=64 VGPR, 4 blk/CU, XCD-balanced)
//                      + NEW epilogue: fold slice partials through Wv ->
//                      headsp_s[j] (128 floats) instead of wembp_s (1024).
//  k4_fused (B x1024): dinv -> heads = dinv * sum_s headsp -> glimpse -> g2
//                      -> logits (dynamic trip) -> max-free log_softmax
// ws: qpt[B][1024] | headsp[B][8][128] | stats[B][64] | idx[B][1024] | cnt[B]
// Shared softmax shift C=0 (|compat| << 80; fminf guard) -> plain-sum merge.
// Lessons: dispatch boundary ~2-3us (R16); (512,4) caps VGPR=64 (R11);
// blockIdx%8 = XCD -> balance slices (R13); heads is linear in wembp_s.
// ============================================================================

// ---------------- K1': mean + query + qproj + mask compaction ----------------
__global__ __launch_bounds__(1024, 4)
void k1_fused(const float* __restrict__ emb, const float* __restrict__ stepc,
              const void* __restrict__ maskp,
              const float* __restrict__ Wn, const float* __restrict__ Wf,
              const float* __restrict__ Ws,
              float* __restrict__ qpt, int* __restrict__ idxv, int* __restrict__ cntv) {
    const int b = blockIdx.x, t = threadIdx.x;
    const int w = t >> 6, lane = t & 63;
    const float* eb = emb + (size_t)b * (NN * DD);
    __shared__ __align__(16) float S[4096];
    __shared__ float s_mean[128], s_q[128];
    __shared__ int s_misint;
    __shared__ unsigned long long s_bal[16];
    __shared__ int s_woff[16];
    if (t == 0) {   // mask layout probe (int32: bytes 1 mod 4 all 0)
        const unsigned char* mb8 = (const unsigned char*)maskp;
        int any = 0;
        for (int k = 0; k < 64; ++k) any |= mb8[4 * k + 1];
        s_misint = (any == 0) ? 1 : 0;
    }
    {   // mean: 32 row-groups x 32 float4-columns
        const int c4 = t & 31, g = t >> 5;
        float4 a = make_float4(0.f, 0.f, 0.f, 0.f);
        for (int r = g; r < NN; r += 32) {
            const float4 v = *(const float4*)(eb + (size_t)r * DD + c4 * 4);
            a.x += v.x; a.y += v.y; a.z += v.z; a.w += v.w;
        }
        ((float4*)S)[g * 32 + c4] = a;
    }
    __syncthreads();
    if (t < 128) {
        float v = 0.f;
        #pragma unroll
        for (int g = 0; g < 32; ++g) v += S[g * 128 + t];
        s_mean[t] = v * (1.0f / (float)NN);
    }
    __syncthreads();
    {   // query[d] = mean.Wf[:,d] + sc.Ws[:,d], 8-way split
        const int d = t & 127, p = t >> 7;
        float a = 0.f;
        for (int i = 16 * p; i < 16 * p + 16; ++i)
            a = fmaf(s_mean[i], Wf[i * DD + d], a);
        const float* scb = stepc + (size_t)b * CTXN;
        const int c0 = 16 * p, c1 = (p == 7) ? CTXN : 16 * p + 16;
        for (int c = c0; c < c1; ++c)
            a = fmaf(scb[c], Ws[c * DD + d], a);
        S[p * 128 + d] = a;
    }
    __syncthreads();
    if (t < 128) {
        float v = 0.f;
        #pragma unroll
        for (int p = 0; p < 8; ++p) v += S[p * 128 + t];
        s_q[t] = v;
    }
    __syncthreads();
    {   // qproj one-shot: thread (i = t&127, h = t>>7)
        const int i = t & 127, h = t >> 7;
        float a = 0.f;
        #pragma unroll
        for (int j = 0; j < 16; ++j)
            a = fmaf(Wn[i * 384 + h * 16 + j], s_q[h * 16 + j], a);
        qpt[(size_t)b * 1024 + h * 128 + i] = a * 0.25f;  // 1/sqrt(16)
    }
    // ---- compaction: unmasked row indices, ascending ----
    {
        const unsigned char* mk8 = (const unsigned char*)maskp + (size_t)b * NN;
        const int* mk32 = (const int*)maskp + (size_t)b * NN;
        int um = 0;
        if (t < NN) um = s_misint ? (mk32[t] == 0) : (mk8[t] == 0);
        const unsigned long long bal = __ballot(um);
        if (lane == 0) s_bal[w] = bal;
        __syncthreads();
        if (t == 0) {
            int o = 0;
            #pragma unroll
            for (int w2 = 0; w2 < 16; ++w2) {
                s_woff[w2] = o;
                o += (int)__popcll(s_bal[w2]);
            }
            cntv[b] = o;
        }
        __syncthreads();
        if (um) {
            const int pos = s_woff[w] +
                (int)__popcll(bal & ((lane == 0) ? 0ULL : (~0ULL >> (64 - lane))));
            idxv[(size_t)b * 1024 + pos] = t;
        }
    }
}

// ---------------- KB: slim streaming + headsp fold epilogue ----------------
// lane = (rg, cl): rg in [0,4) = head PAIR (heads 2rg, 2rg+1); cl = col octet.
// Wave w does compact position it*8 + w. <=64 VGPR; 4 blk/CU (LDS 38.6 KB).
__global__ __launch_bounds__(512, 4)
void kB_stream(const float* __restrict__ emb, const float* __restrict__ qpt,
               const float* __restrict__ Wn,
               const int* __restrict__ idxv, const int* __restrict__ cntv,
               float* __restrict__ headsp, float* __restrict__ stats) {
    const int b = blockIdx.x >> 3, s = blockIdx.x & 7;
    const int t = threadIdx.x, w = t >> 6, lane = t & 63;
    const int rg = lane >> 4, cl = lane & 15;
    const int cnt = cntv[b];
    const int lo = (s * cnt) >> 3;          // balanced: slice s gets ~cnt/8 rows
    const int hi = ((s + 1) * cnt) >> 3;
    const int nrows = hi - lo;              // <= 125
    const float* eb = emb + (size_t)b * (NN * DD);
    __shared__ __align__(16) float s_qpT[1024];         // 4 KB
    __shared__ __align__(16) float s_part[8 * 8 * 132]; // 33.8 KB; reused in epilogue
    __shared__ float s_sumw[64];
    __shared__ int s_idx[128];
    for (int i = t; i < 1024; i += 512) s_qpT[i] = qpt[(size_t)b * 1024 + i];
    if (t < 128) s_idx[t] = (t < nrows) ? idxv[(size_t)b * 1024 + lo + t] : 0;
    __syncthreads();
    const int h0 = 2 * rg, h1 = 2 * rg + 1;
    const float4 qa0 = *(const float4*)&s_qpT[h0 * 128 + cl * 8];
    const float4 qa1 = *(const float4*)&s_qpT[h0 * 128 + cl * 8 + 4];
    const float4 qb0 = *(const float4*)&s_qpT[h1 * 128 + cl * 8];
    const float4 qb1 = *(const float4*)&s_qpT[h1 * 128 + cl * 8 + 4];
    float4 a0A = make_float4(0.f,0.f,0.f,0.f), a0B = a0A;   // head h0, cols lo/hi
    float4 a1A = a0A, a1B = a0A;                            // head h1
    float ps0 = 0.f, ps1 = 0.f;
    const int niter = (nrows + 7) >> 3;     // uniform; ~8 typical
    for (int it = 0; it < niter; ++it) {
        const int rp = it * 8 + w;          // wave-w's compact position
        const bool valid = (rp < nrows);
        const int n = s_idx[rp & 127];
        float4 e0 = make_float4(0.f,0.f,0.f,0.f), e1 = e0;
        if (valid) {
            e0 = *(const float4*)(eb + (size_t)n * DD + cl * 8);
            e1 = *(const float4*)(eb + (size_t)n * DD + cl * 8 + 4);
        }
        float c0 = e0.x * qa0.x;
        c0 = fmaf(e0.y, qa0.y, c0); c0 = fmaf(e0.z, qa0.z, c0); c0 = fmaf(e0.w, qa0.w, c0);
        c0 = fmaf(e1.x, qa1.x, c0); c0 = fmaf(e1.y, qa1.y, c0);
        c0 = fmaf(e1.z, qa1.z, c0); c0 = fmaf(e1.w, qa1.w, c0);
        float c1 = e0.x * qb0.x;
        c1 = fmaf(e0.y, qb0.y, c1); c1 = fmaf(e0.z, qb0.z, c1); c1 = fmaf(e0.w, qb0.w, c1);
        c1 = fmaf(e1.x, qb1.x, c1); c1 = fmaf(e1.y, qb1.y, c1);
        c1 = fmaf(e1.z, qb1.z, c1); c1 = fmaf(e1.w, qb1.w, c1);
        c0 += __shfl_xor(c0, 1, 16); c1 += __shfl_xor(c1, 1, 16);
        c0 += __shfl_xor(c0, 2, 16); c1 += __shfl_xor(c1, 2, 16);
        c0 += __shfl_xor(c0, 4, 16); c1 += __shfl_xor(c1, 4, 16);
        c0 += __shfl_xor(c0, 8, 16); c1 += __shfl_xor(c1, 8, 16);
        const float p0 = valid ? expf(fminf(c0, 80.f)) : 0.f;
        const float p1 = valid ? expf(fminf(c1, 80.f)) : 0.f;
        ps0 += p0; ps1 += p1;
        a0A.x = fmaf(p0, e0.x, a0A.x); a0A.y = fmaf(p0, e0.y, a0A.y);
        a0A.z = fmaf(p0, e0.z, a0A.z); a0A.w = fmaf(p0, e0.w, a0A.w);
        a0B.x = fmaf(p0, e1.x, a0B.x); a0B.y = fmaf(p0, e1.y, a0B.y);
        a0B.z = fmaf(p0, e1.z, a0B.z); a0B.w = fmaf(p0, e1.w, a0B.w);
        a1A.x = fmaf(p1, e0.x, a1A.x); a1A.y = fmaf(p1, e0.y, a1A.y);
        a1A.z = fmaf(p1, e0.z, a1A.z); a1A.w = fmaf(p1, e0.w, a1A.w);
        a1B.x = fmaf(p1, e1.x, a1B.x); a1B.y = fmaf(p1, e1.y, a1B.y);
        a1B.z = fmaf(p1, e1.z, a1B.z); a1B.w = fmaf(p1, e1.w, a1B.w);
    }
    // direct per-lane write: lane covers (h0,h1) x cols cl*8..+8
    *(float4*)&s_part[(w * 8 + h0) * 132 + cl * 8]     = a0A;
    *(float4*)&s_part[(w * 8 + h0) * 132 + cl * 8 + 4] = a0B;
    *(float4*)&s_part[(w * 8 + h1) * 132 + cl * 8]     = a1A;
    *(float4*)&s_part[(w * 8 + h1) * 132 + cl * 8 + 4] = a1B;
    if (cl == 0) { s_sumw[w * 8 + h0] = ps0; s_sumw[w * 8 + h1] = ps1; }
    __syncthreads();
    // ---- reduce wave partials into registers, stash wemb_s into s_part[0..1024) ----
    float vres0, vres1;
    {
        const int i0 = t, i1 = t + 512;               // [h][c] flat, 1024 elems
        const int hA = i0 >> 7, cA = i0 & 127;
        const int hB = i1 >> 7, cB = i1 & 127;
        float v0 = 0.f, v1 = 0.f;
        #pragma unroll
        for (int w2 = 0; w2 < 8; ++w2) {
            v0 += s_part[(w2 * 8 + hA) * 132 + cA];
            v1 += s_part[(w2 * 8 + hB) * 132 + cB];
        }
        vres0 = v0; vres1 = v1;
    }
    __syncthreads();
    s_part[t]       = vres0;                          // s_wemb[h*128 + c]
    s_part[t + 512] = vres1;
    __syncthreads();
    // ---- headsp_s[j] = sum_i Wv[i,j] * wemb_s[j>>4][i], 4-way i-split ----
    {
        const int j = t & 127, p = t >> 7;
        const int h = j >> 4;
        float a = 0.f;
        for (int i = 32 * p; i < 32 * p + 32; ++i)
            a = fmaf(Wn[i * 384 + 128 + j], s_part[h * 128 + i], a);
        s_part[1024 + p * 128 + j] = a;
    }
    __syncthreads();
    if (t < 128)
        headsp[(size_t)b * 1024 + s * 128 + t] =
            s_part[1024 + t] + s_part[1024 + 128 + t] +
            s_part[1024 + 256 + t] + s_part[1024 + 384 + t];
    if (t < 8) {
        float v = 0.f;
        #pragma unroll
        for (int w2 = 0; w2 < 8; ++w2) v += s_sumw[w2 * 8 + t];
        stats[(size_t)b * 64 + s * 8 + t] = v;
    }
}

// ---------------- K4': heads merge -> glimpse -> g2 -> logits -> log_softmax ----------------
__global__ __launch_bounds__(1024, 4)
void k4_fused(const float* __restrict__ emb, const float* __restrict__ headsp,
              const float* __restrict__ stats,
              const float* __restrict__ Wn, const float* __restrict__ Wo,
              const int* __restrict__ idxv, const int* __restrict__ cntv,
              float* __restrict__ out) {
    const int b = blockIdx.x, t = threadIdx.x;
    const int w = t >> 6, lane = t & 63;
    const int rg = lane >> 4, cl = lane & 15;
    const float* eb = emb + (size_t)b * (NN * DD);
    __shared__ float s_dinv[8];
    __shared__ __align__(16) float s_red[1024];
    __shared__ float s_h[128], s_gl[128], s_g2[128];
    __shared__ float s_logits[1000];
    __shared__ int s_idxf[1024];
    __shared__ float s_r2[32];
    __shared__ float s_lse;
    const int cnt = cntv[b];
    if (t < NN) s_logits[t] = NEG_BIG;           // masked rows stay NEG_BIG
    s_idxf[t] = (t < cnt) ? idxv[(size_t)b * 1024 + t] : 0;
    // ---- dinv[h] = 1 / sum_s psum_s[h] (shared shift C=0) ----
    if (t < 8) {
        float den = 0.f;
        #pragma unroll
        for (int ss = 0; ss < 8; ++ss) den += stats[(size_t)b * 64 + ss * 8 + t];
        s_dinv[t] = 1.0f / den;
    }
    __syncthreads();
    // ---- heads[j] = dinv[j>>4] * sum_s headsp_s[j] (linearity fold) ----
    if (t < 128) {
        float v = 0.f;
        #pragma unroll
        for (int ss = 0; ss < 8; ++ss) v += headsp[(size_t)b * 1024 + ss * 128 + t];
        s_h[t] = v * s_dinv[t >> 4];
    }
    __syncthreads();
    {   // glimpse[d] = sum_j heads[j] Wo[j,d], 8-way j-split
        const int d = t & 127, p = t >> 7;
        float a = 0.f;
        for (int j = 16 * p; j < 16 * p + 16; ++j)
            a = fmaf(s_h[j], Wo[j * DD + d], a);
        s_red[p * 128 + d] = a;
    }
    __syncthreads();
    if (t < 128) {
        float v = 0.f;
        #pragma unroll
        for (int p = 0; p < 8; ++p) v += s_red[p * 128 + t];
        s_gl[t] = v;
    }
    __syncthreads();
    {   // g2[i] = (1/sqrt(128)) sum_d Wl[i,d] glimpse[d]
        const int i = t & 127, p = t >> 7;
        float a = 0.f;
        for (int d = 16 * p; d < 16 * p + 16; ++d)
            a = fmaf(Wn[i * 384 + 256 + d], s_gl[d], a);
        s_red[p * 128 + i] = a;
    }
    __syncthreads();
    if (t < 128) {
        float v = 0.f;
        #pragma unroll
        for (int p = 0; p < 8; ++p) v += s_red[p * 128 + t];
        s_g2[t] = v * 0.08838834764831845f;
    }
    __syncthreads();
    // ---- logits over compacted rows: dynamic trip count ----
    {
        const float4 ga = *(const float4*)&s_g2[cl * 8];
        const float4 gb = *(const float4*)&s_g2[cl * 8 + 4];
        const int niterL = (cnt + 63) >> 6;     // 64 positions per iteration
        for (int it = 0; it < niterL; ++it) {
            const int pos = it * 64 + w * 4 + rg;
            const bool valid = (pos < cnt);
            const int n = s_idxf[pos & 1023];
            float a = 0.f;
            if (valid) {
                const float4 e0 = *(const float4*)(eb + (size_t)n * DD + cl * 8);
                const float4 e1 = *(const float4*)(eb + (size_t)n * DD + cl * 8 + 4);
                a = e0.x * ga.x;
                a = fmaf(e0.y, ga.y, a);
                a = fmaf(e0.z, ga.z, a);
                a = fmaf(e0.w, ga.w, a);
                a = fmaf(e1.x, gb.x, a);
                a = fmaf(e1.y, gb.y, a);
                a = fmaf(e1.z, gb.z, a);
                a = fmaf(e1.w, gb.w, a);
            }
            a += __shfl_xor(a, 1, 16);
            a += __shfl_xor(a, 2, 16);
            a += __shfl_xor(a, 4, 16);
            a += __shfl_xor(a, 8, 16);
            if (cl == 0 && valid)
                s_logits[n] = 10.0f * tanhf(a);
        }
    }
    __syncthreads();
    // ---- max-free log_softmax: |logits| <= 10 -> exp in [4.5e-5, 2.2e4];
    //      masked rows: expf(NEG_BIG) = 0 exactly.
    {
        float sum = (t < NN) ? expf(s_logits[t]) : 0.f;
        #pragma unroll
        for (int o = 32; o; o >>= 1) sum += __shfl_xor(sum, o, 64);
        if (lane == 0) s_r2[w] = sum;
        __syncthreads();
        if (t == 0) {
            float ss = 0.f;
            #pragma unroll
            for (int i = 0; i < 16; ++i) ss += s_r2[i];
            s_lse = logf(ss);
        }
        __syncthreads();
        if (t < NN) out[(size_t)b * NN + t] = s_logits[t] - s_lse;
    }
}

extern "C" void kernel_launch(void* const* d_in, const int* in_sizes, int n_in,
                              void* d_out, int out_size, void* d_ws, size_t ws_size,
                              hipStream_t stream) {
    const float* emb   = (const float*)d_in[0];
    const float* stepc = (const float*)d_in[1];
    const void*  mask  = (const void*)d_in[2];
    const float* Wn = (const float*)d_in[3];
    const float* Wf = (const float*)d_in[4];
    const float* Ws = (const float*)d_in[5];
    const float* Wo = (const float*)d_in[6];
    float* out = (float*)d_out;
    const int B = in_sizes[0] / (NN * DD);  // 256

    float* wsf = (float*)d_ws;
    const size_t n_qpt   = (size_t)B * 1024;
    const size_t n_hp    = (size_t)B * 1024;
    const size_t n_stats = (size_t)B * 64;
    const size_t n_idx   = (size_t)B * 1024;

    float* qpt    = wsf;
    float* headsp = qpt + n_qpt;
    float* stats  = headsp + n_hp;
    int*   idxv   = (int*)(stats + n_stats);
    int*   cntv   = idxv + n_idx;

    k1_fused <<<B,     1024, 0, stream>>>(emb, stepc, mask, Wn, Wf, Ws, qpt, idxv, cntv);
    kB_stream<<<B * 8, 512,  0, stream>>>(emb, qpt, Wn, idxv, cntv, headsp, stats);
    k4_fused <<<B,     1024, 0, stream>>>(emb, headsp, stats, Wn, Wo, idxv, cntv, out);
}

// Round 19
// 78.334 us; speedup vs baseline: 1.1331x; 1.0264x over previous
//
#include <hip/hip_runtime.h>
#include <math.h>

#define NN   1000
#define DD   128
#define CTXN 130
#define NEG_BIG (-1.0e30f)

// fast tanh via __expf; exact +-1 at saturation, no NaN (clamp keeps exp finite)
__device__ __forceinline__ float fast_tanh(float a) {
    a = fminf(fmaxf(a, -20.f), 20.f);
    const float ex = __expf(-2.0f * a);
    return (1.0f - ex) / (1.0f + ex);
}

// ============================================================================
// 3-dispatch pipeline (R18 champion + fast transcendentals + branchless loops):
//  k1_fused (B x1024): emb -> mean -> query -> qproj[h][i] + row compaction
//  kB       (B*8x512): slim streaming over balanced compacted rows (2 heads x
//                      8 cols per lane, <=64 VGPR, 4 blk/CU, XCD-balanced)
//                      + headsp fold epilogue (slice partials through Wv).
//  k4_fused (B x1024): dinv -> heads -> glimpse -> g2 -> logits (dynamic trip,
//                      branchless main) -> max-free log_softmax
// ws: qpt[B][1024] | headsp[B][8][128] | stats[B][64] | idx[B][1024] | cnt[B]
// Shared softmax shift C=0 (|compat| << 80; fminf guard) -> plain-sum merge.
// Lessons: dispatch boundary ~2-3us (R16); (512,4) caps VGPR=64 (R11);
// blockIdx%8 = XCD -> balance slices (R13); heads linear in wembp_s (R18).
// ============================================================================

// ---------------- K1': mean + query + qproj + mask compaction ----------------
__global__ __launch_bounds__(1024, 4)
void k1_fused(const float* __restrict__ emb, const float* __restrict__ stepc,
              const void* __restrict__ maskp,
              const float* __restrict__ Wn, const float* __restrict__ Wf,
              const float* __restrict__ Ws,
              float* __restrict__ qpt, int* __restrict__ idxv, int* __restrict__ cntv) {
    const int b = blockIdx.x, t = threadIdx.x;
    const int w = t >> 6, lane = t & 63;
    const float* eb = emb + (size_t)b * (NN * DD);
    __shared__ __align__(16) float S[4096];
    __shared__ float s_mean[128], s_q[128];
    __shared__ int s_misint;
    __shared__ unsigned long long s_bal[16];
    __shared__ int s_woff[16];
    if (t == 0) {   // mask layout probe (int32: bytes 1 mod 4 all 0)
        const unsigned char* mb8 = (const unsigned char*)maskp;
        int any = 0;
        for (int k = 0; k < 64; ++k) any |= mb8[4 * k + 1];
        s_misint = (any == 0) ? 1 : 0;
    }
    {   // mean: 32 row-groups x 32 float4-columns
        const int c4 = t & 31, g = t >> 5;
        float4 a = make_float4(0.f, 0.f, 0.f, 0.f);
        for (int r = g; r < NN; r += 32) {
            const float4 v = *(const float4*)(eb + (size_t)r * DD + c4 * 4);
            a.x += v.x; a.y += v.y; a.z += v.z; a.w += v.w;
        }
        ((float4*)S)[g * 32 + c4] = a;
    }
    __syncthreads();
    if (t < 128) {
        float v = 0.f;
        #pragma unroll
        for (int g = 0; g < 32; ++g) v += S[g * 128 + t];
        s_mean[t] = v * (1.0f / (float)NN);
    }
    __syncthreads();
    {   // query[d] = mean.Wf[:,d] + sc.Ws[:,d], 8-way split
        const int d = t & 127, p = t >> 7;
        float a = 0.f;
        for (int i = 16 * p; i < 16 * p + 16; ++i)
            a = fmaf(s_mean[i], Wf[i * DD + d], a);
        const float* scb = stepc + (size_t)b * CTXN;
        const int c0 = 16 * p, c1 = (p == 7) ? CTXN : 16 * p + 16;
        for (int c = c0; c < c1; ++c)
            a = fmaf(scb[c], Ws[c * DD + d], a);
        S[p * 128 + d] = a;
    }
    __syncthreads();
    if (t < 128) {
        float v = 0.f;
        #pragma unroll
        for (int p = 0; p < 8; ++p) v += S[p * 128 + t];
        s_q[t] = v;
    }
    __syncthreads();
    {   // qproj one-shot: thread (i = t&127, h = t>>7)
        const int i = t & 127, h = t >> 7;
        float a = 0.f;
        #pragma unroll
        for (int j = 0; j < 16; ++j)
            a = fmaf(Wn[i * 384 + h * 16 + j], s_q[h * 16 + j], a);
        qpt[(size_t)b * 1024 + h * 128 + i] = a * 0.25f;  // 1/sqrt(16)
    }
    // ---- compaction: unmasked row indices, ascending ----
    {
        const unsigned char* mk8 = (const unsigned char*)maskp + (size_t)b * NN;
        const int* mk32 = (const int*)maskp + (size_t)b * NN;
        int um = 0;
        if (t < NN) um = s_misint ? (mk32[t] == 0) : (mk8[t] == 0);
        const unsigned long long bal = __ballot(um);
        if (lane == 0) s_bal[w] = bal;
        __syncthreads();
        if (t == 0) {
            int o = 0;
            #pragma unroll
            for (int w2 = 0; w2 < 16; ++w2) {
                s_woff[w2] = o;
                o += (int)__popcll(s_bal[w2]);
            }
            cntv[b] = o;
        }
        __syncthreads();
        if (um) {
            const int pos = s_woff[w] +
                (int)__popcll(bal & ((lane == 0) ? 0ULL : (~0ULL >> (64 - lane))));
            idxv[(size_t)b * 1024 + pos] = t;
        }
    }
}

// ---------------- KB: slim streaming + headsp fold epilogue ----------------
// lane = (rg, cl): rg in [0,4) = head PAIR (heads 2rg, 2rg+1); cl = col octet.
// Wave w does compact position it*8 + w. <=64 VGPR; 4 blk/CU (LDS 38.6 KB).
__global__ __launch_bounds__(512, 4)
void kB_stream(const float* __restrict__ emb, const float* __restrict__ qpt,
               const float* __restrict__ Wn,
               const int* __restrict__ idxv, const int* __restrict__ cntv,
               float* __restrict__ headsp, float* __restrict__ stats) {
    const int b = blockIdx.x >> 3, s = blockIdx.x & 7;
    const int t = threadIdx.x, w = t >> 6, lane = t & 63;
    const int rg = lane >> 4, cl = lane & 15;
    const int cnt = cntv[b];
    const int lo = (s * cnt) >> 3;          // balanced: slice s gets ~cnt/8 rows
    const int hi = ((s + 1) * cnt) >> 3;
    const int nrows = hi - lo;              // <= 125
    const float* eb = emb + (size_t)b * (NN * DD);
    __shared__ __align__(16) float s_qpT[1024];         // 4 KB
    __shared__ __align__(16) float s_part[8 * 8 * 132]; // 33.8 KB; reused in epilogue
    __shared__ float s_sumw[64];
    __shared__ int s_idx[128];
    for (int i = t; i < 1024; i += 512) s_qpT[i] = qpt[(size_t)b * 1024 + i];
    if (t < 128) s_idx[t] = (t < nrows) ? idxv[(size_t)b * 1024 + lo + t] : 0;
    __syncthreads();
    const int h0 = 2 * rg, h1 = 2 * rg + 1;
    const float4 qa0 = *(const float4*)&s_qpT[h0 * 128 + cl * 8];
    const float4 qa1 = *(const float4*)&s_qpT[h0 * 128 + cl * 8 + 4];
    const float4 qb0 = *(const float4*)&s_qpT[h1 * 128 + cl * 8];
    const float4 qb1 = *(const float4*)&s_qpT[h1 * 128 + cl * 8 + 4];
    float4 a0A = make_float4(0.f,0.f,0.f,0.f), a0B = a0A;   // head h0, cols lo/hi
    float4 a1A = a0A, a1B = a0A;                            // head h1
    float ps0 = 0.f, ps1 = 0.f;
    // ---- branchless main iterations (all 8 wave-positions valid) ----
    const int mainIt = nrows >> 3;
    for (int it = 0; it < mainIt; ++it) {
        const int rp = it * 8 + w;
        const int n = s_idx[rp];
        const float4 e0 = *(const float4*)(eb + (size_t)n * DD + cl * 8);
        const float4 e1 = *(const float4*)(eb + (size_t)n * DD + cl * 8 + 4);
        float c0 = e0.x * qa0.x;
        c0 = fmaf(e0.y, qa0.y, c0); c0 = fmaf(e0.z, qa0.z, c0); c0 = fmaf(e0.w, qa0.w, c0);
        c0 = fmaf(e1.x, qa1.x, c0); c0 = fmaf(e1.y, qa1.y, c0);
        c0 = fmaf(e1.z, qa1.z, c0); c0 = fmaf(e1.w, qa1.w, c0);
        float c1 = e0.x * qb0.x;
        c1 = fmaf(e0.y, qb0.y, c1); c1 = fmaf(e0.z, qb0.z, c1); c1 = fmaf(e0.w, qb0.w, c1);
        c1 = fmaf(e1.x, qb1.x, c1); c1 = fmaf(e1.y, qb1.y, c1);
        c1 = fmaf(e1.z, qb1.z, c1); c1 = fmaf(e1.w, qb1.w, c1);
        c0 += __shfl_xor(c0, 1, 16); c1 += __shfl_xor(c1, 1, 16);
        c0 += __shfl_xor(c0, 2, 16); c1 += __shfl_xor(c1, 2, 16);
        c0 += __shfl_xor(c0, 4, 16); c1 += __shfl_xor(c1, 4, 16);
        c0 += __shfl_xor(c0, 8, 16); c1 += __shfl_xor(c1, 8, 16);
        const float p0 = __expf(fminf(c0, 80.f));
        const float p1 = __expf(fminf(c1, 80.f));
        ps0 += p0; ps1 += p1;
        a0A.x = fmaf(p0, e0.x, a0A.x); a0A.y = fmaf(p0, e0.y, a0A.y);
        a0A.z = fmaf(p0, e0.z, a0A.z); a0A.w = fmaf(p0, e0.w, a0A.w);
        a0B.x = fmaf(p0, e1.x, a0B.x); a0B.y = fmaf(p0, e1.y, a0B.y);
        a0B.z = fmaf(p0, e1.z, a0B.z); a0B.w = fmaf(p0, e1.w, a0B.w);
        a1A.x = fmaf(p1, e0.x, a1A.x); a1A.y = fmaf(p1, e0.y, a1A.y);
        a1A.z = fmaf(p1, e0.z, a1A.z); a1A.w = fmaf(p1, e0.w, a1A.w);
        a1B.x = fmaf(p1, e1.x, a1B.x); a1B.y = fmaf(p1, e1.y, a1B.y);
        a1B.z = fmaf(p1, e1.z, a1B.z); a1B.w = fmaf(p1, e1.w, a1B.w);
    }
    // ---- guarded tail (at most one iteration) ----
    if (mainIt * 8 < nrows) {
        const int rp = mainIt * 8 + w;
        const bool valid = (rp < nrows);
        const int n = s_idx[rp & 127];
        float4 e0 = make_float4(0.f,0.f,0.f,0.f), e1 = e0;
        if (valid) {
            e0 = *(const float4*)(eb + (size_t)n * DD + cl * 8);
            e1 = *(const float4*)(eb + (size_t)n * DD + cl * 8 + 4);
        }
        float c0 = e0.x * qa0.x;
        c0 = fmaf(e0.y, qa0.y, c0); c0 = fmaf(e0.z, qa0.z, c0); c0 = fmaf(e0.w, qa0.w, c0);
        c0 = fmaf(e1.x, qa1.x, c0); c0 = fmaf(e1.y, qa1.y, c0);
        c0 = fmaf(e1.z, qa1.z, c0); c0 = fmaf(e1.w, qa1.w, c0);
        float c1 = e0.x * qb0.x;
        c1 = fmaf(e0.y, qb0.y, c1); c1 = fmaf(e0.z, qb0.z, c1); c1 = fmaf(e0.w, qb0.w, c1);
        c1 = fmaf(e1.x, qb1.x, c1); c1 = fmaf(e1.y, qb1.y, c1);
        c1 = fmaf(e1.z, qb1.z, c1); c1 = fmaf(e1.w, qb1.w, c1);
        c0 += __shfl_xor(c0, 1, 16); c1 += __shfl_xor(c1, 1, 16);
        c0 += __shfl_xor(c0, 2, 16); c1 += __shfl_xor(c1, 2, 16);
        c0 += __shfl_xor(c0, 4, 16); c1 += __shfl_xor(c1, 4, 16);
        c0 += __shfl_xor(c0, 8, 16); c1 += __shfl_xor(c1, 8, 16);
        const float p0 = valid ? __expf(fminf(c0, 80.f)) : 0.f;
        const float p1 = valid ? __expf(fminf(c1, 80.f)) : 0.f;
        ps0 += p0; ps1 += p1;
        a0A.x = fmaf(p0, e0.x, a0A.x); a0A.y = fmaf(p0, e0.y, a0A.y);
        a0A.z = fmaf(p0, e0.z, a0A.z); a0A.w = fmaf(p0, e0.w, a0A.w);
        a0B.x = fmaf(p0, e1.x, a0B.x); a0B.y = fmaf(p0, e1.y, a0B.y);
        a0B.z = fmaf(p0, e1.z, a0B.z); a0B.w = fmaf(p0, e1.w, a0B.w);
        a1A.x = fmaf(p1, e0.x, a1A.x); a1A.y = fmaf(p1, e0.y, a1A.y);
        a1A.z = fmaf(p1, e0.z, a1A.z); a1A.w = fmaf(p1, e0.w, a1A.w);
        a1B.x = fmaf(p1, e1.x, a1B.x); a1B.y = fmaf(p1, e1.y, a1B.y);
        a1B.z = fmaf(p1, e1.z, a1B.z); a1B.w = fmaf(p1, e1.w, a1B.w);
    }
    // direct per-lane write: lane covers (h0,h1) x cols cl*8..+8
    *(float4*)&s_part[(w * 8 + h0) * 132 + cl * 8]     = a0A;
    *(float4*)&s_part[(w * 8 + h0) * 132 + cl * 8 + 4] = a0B;
    *(float4*)&s_part[(w * 8 + h1) * 132 + cl * 8]     = a1A;
    *(float4*)&s_part[(w * 8 + h1) * 132 + cl * 8 + 4] = a1B;
    if (cl == 0) { s_sumw[w * 8 + h0] = ps0; s_sumw[w * 8 + h1] = ps1; }
    __syncthreads();
    // ---- reduce wave partials, stash wemb_s into s_part[0..1024) ----
    float vres0, vres1;
    {
        const int i0 = t, i1 = t + 512;
        const int hA = i0 >> 7, cA = i0 & 127;
        const int hB = i1 >> 7, cB = i1 & 127;
        float v0 = 0.f, v1 = 0.f;
        #pragma unroll
        for (int w2 = 0; w2 < 8; ++w2) {
            v0 += s_part[(w2 * 8 + hA) * 132 + cA];
            v1 += s_part[(w2 * 8 + hB) * 132 + cB];
        }
        vres0 = v0; vres1 = v1;
    }
    __syncthreads();
    s_part[t]       = vres0;
    s_part[t + 512] = vres1;
    __syncthreads();
    // ---- headsp_s[j] = sum_i Wv[i,j] * wemb_s[j>>4][i], 4-way i-split ----
    {
        const int j = t & 127, p = t >> 7;
        const int h = j >> 4;
        float a = 0.f;
        for (int i = 32 * p; i < 32 * p + 32; ++i)
            a = fmaf(Wn[i * 384 + 128 + j], s_part[h * 128 + i], a);
        s_part[1024 + p * 128 + j] = a;
    }
    __syncthreads();
    if (t < 128)
        headsp[(size_t)b * 1024 + s * 128 + t] =
            s_part[1024 + t] + s_part[1024 + 128 + t] +
            s_part[1024 + 256 + t] + s_part[1024 + 384 + t];
    if (t < 8) {
        float v = 0.f;
        #pragma unroll
        for (int w2 = 0; w2 < 8; ++w2) v += s_sumw[w2 * 8 + t];
        stats[(size_t)b * 64 + s * 8 + t] = v;
    }
}

// ---------------- K4': heads merge -> glimpse -> g2 -> logits -> log_softmax ----------------
__global__ __launch_bounds__(1024, 4)
void k4_fused(const float* __restrict__ emb, const float* __restrict__ headsp,
              const float* __restrict__ stats,
              const float* __restrict__ Wn, const float* __restrict__ Wo,
              const int* __restrict__ idxv, const int* __restrict__ cntv,
              float* __restrict__ out) {
    const int b = blockIdx.x, t = threadIdx.x;
    const int w = t >> 6, lane = t & 63;
    const int rg = lane >> 4, cl = lane & 15;
    const float* eb = emb + (size_t)b * (NN * DD);
    __shared__ float s_dinv[8];
    __shared__ __align__(16) float s_red[1024];
    __shared__ float s_h[128], s_gl[128], s_g2[128];
    __shared__ float s_logits[1000];
    __shared__ int s_idxf[1024];
    __shared__ float s_r2[32];
    __shared__ float s_lse;
    const int cnt = cntv[b];
    if (t < NN) s_logits[t] = NEG_BIG;           // masked rows stay NEG_BIG
    s_idxf[t] = (t < cnt) ? idxv[(size_t)b * 1024 + t] : 0;
    // ---- dinv[h] = 1 / sum_s psum_s[h] (shared shift C=0) ----
    if (t < 8) {
        float den = 0.f;
        #pragma unroll
        for (int ss = 0; ss < 8; ++ss) den += stats[(size_t)b * 64 + ss * 8 + t];
        s_dinv[t] = 1.0f / den;
    }
    __syncthreads();
    // ---- heads[j] = dinv[j>>4] * sum_s headsp_s[j] (linearity fold) ----
    if (t < 128) {
        float v = 0.f;
        #pragma unroll
        for (int ss = 0; ss < 8; ++ss) v += headsp[(size_t)b * 1024 + ss * 128 + t];
        s_h[t] = v * s_dinv[t >> 4];
    }
    __syncthreads();
    {   // glimpse[d] = sum_j heads[j] Wo[j,d], 8-way j-split
        const int d = t & 127, p = t >> 7;
        float a = 0.f;
        for (int j = 16 * p; j < 16 * p + 16; ++j)
            a = fmaf(s_h[j], Wo[j * DD + d], a);
        s_red[p * 128 + d] = a;
    }
    __syncthreads();
    if (t < 128) {
        float v = 0.f;
        #pragma unroll
        for (int p = 0; p < 8; ++p) v += s_red[p * 128 + t];
        s_gl[t] = v;
    }
    __syncthreads();
    {   // g2[i] = (1/sqrt(128)) sum_d Wl[i,d] glimpse[d]
        const int i = t & 127, p = t >> 7;
        float a = 0.f;
        for (int d = 16 * p; d < 16 * p + 16; ++d)
            a = fmaf(Wn[i * 384 + 256 + d], s_gl[d], a);
        s_red[p * 128 + i] = a;
    }
    __syncthreads();
    if (t < 128) {
        float v = 0.f;
        #pragma unroll
        for (int p = 0; p < 8; ++p) v += s_red[p * 128 + t];
        s_g2[t] = v * 0.08838834764831845f;
    }
    __syncthreads();
    // ---- logits over compacted rows: branchless main + guarded tail ----
    {
        const float4 ga = *(const float4*)&s_g2[cl * 8];
        const float4 gb = *(const float4*)&s_g2[cl * 8 + 4];
        const int mainL = cnt >> 6;             // 64 positions per iteration
        for (int it = 0; it < mainL; ++it) {
            const int pos = it * 64 + w * 4 + rg;   // pos < cnt guaranteed
            const int n = s_idxf[pos];
            const float4 e0 = *(const float4*)(eb + (size_t)n * DD + cl * 8);
            const float4 e1 = *(const float4*)(eb + (size_t)n * DD + cl * 8 + 4);
            float a = e0.x * ga.x;
            a = fmaf(e0.y, ga.y, a);
            a = fmaf(e0.z, ga.z, a);
            a = fmaf(e0.w, ga.w, a);
            a = fmaf(e1.x, gb.x, a);
            a = fmaf(e1.y, gb.y, a);
            a = fmaf(e1.z, gb.z, a);
            a = fmaf(e1.w, gb.w, a);
            a += __shfl_xor(a, 1, 16);
            a += __shfl_xor(a, 2, 16);
            a += __shfl_xor(a, 4, 16);
            a += __shfl_xor(a, 8, 16);
            if (cl == 0)
                s_logits[n] = 10.0f * fast_tanh(a);
        }
        if (mainL * 64 < cnt) {                 // guarded tail
            const int pos = mainL * 64 + w * 4 + rg;
            const bool valid = (pos < cnt);
            const int n = s_idxf[pos & 1023];
            float a = 0.f;
            if (valid) {
                const float4 e0 = *(const float4*)(eb + (size_t)n * DD + cl * 8);
                const float4 e1 = *(const float4*)(eb + (size_t)n * DD + cl * 8 + 4);
                a = e0.x * ga.x;
                a = fmaf(e0.y, ga.y, a);
                a = fmaf(e0.z, ga.z, a);
                a = fmaf(e0.w, ga.w, a);
                a = fmaf(e1.x, gb.x, a);
                a = fmaf(e1.y, gb.y, a);
                a = fmaf(e1.z, gb.z, a);
                a = fmaf(e1.w, gb.w, a);
            }
            a += __shfl_xor(a, 1, 16);
            a += __shfl_xor(a, 2, 16);
            a += __shfl_xor(a, 4, 16);
            a += __shfl_xor(a, 8, 16);
            if (cl == 0 && valid)
                s_logits[n] = 10.0f * fast_tanh(a);
        }
    }
    __syncthreads();
    // ---- max-free log_softmax: |logits| <= 10 -> exp in [4.5e-5, 2.2e4];
    //      masked rows: __expf(NEG_BIG) = 0 exactly.
    {
        float sum = (t < NN) ? __expf(s_logits[t]) : 0.f;
        #pragma unroll
        for (int o = 32; o; o >>= 1) sum += __shfl_xor(sum, o, 64);
        if (lane == 0) s_r2[w] = sum;
        __syncthreads();
        if (t == 0) {
            float ss = 0.f;
            #pragma unroll
            for (int i = 0; i < 16; ++i) ss += s_r2[i];
            s_lse = logf(ss);
        }
        __syncthreads();
        if (t < NN) out[(size_t)b * NN + t] = s_logits[t] - s_lse;
    }
}

extern "C" void kernel_launch(void* const* d_in, const int* in_sizes, int n_in,
                              void* d_out, int out_size, void* d_ws, size_t ws_size,
                              hipStream_t stream) {
    const float* emb   = (const float*)d_in[0];
    const float* stepc = (const float*)d_in[1];
    const void*  mask  = (const void*)d_in[2];
    const float* Wn = (const float*)d_in[3];
    const float* Wf = (const float*)d_in[4];
    const float* Ws = (const float*)d_in[5];
    const float* Wo = (const float*)d_in[6];
    float* out = (float*)d_out;
    const int B = in_sizes[0] / (NN * DD);  // 256

    float* wsf = (float*)d_ws;
    const size_t n_qpt   = (size_t)B * 1024;
    const size_t n_hp    = (size_t)B * 1024;
    const size_t n_stats = (size_t)B * 64;
    const size_t n_idx   = (size_t)B * 1024;

    float* qpt    = wsf;
    float* headsp = qpt + n_qpt;
    float* stats  = headsp + n_hp;
    int*   idxv   = (int*)(stats + n_stats);
    int*   cntv   = idxv + n_idx;

    k1_fused <<<B,     1024, 0, stream>>>(emb, stepc, mask, Wn, Wf, Ws, qpt, idxv, cntv);
    kB_stream<<<B * 8, 512,  0, stream>>>(emb, qpt, Wn, idxv, cntv, headsp, stats);
    k4_fused <<<B,     1024, 0, stream>>>(emb, headsp, stats, Wn, Wo, idxv, cntv, out);
}